// Round 16
// baseline (2409.732 us; speedup 1.0000x reference)
//
#include <hip/hip_runtime.h>
#include <stdint.h>

typedef __attribute__((ext_vector_type(8))) short bf16x8;
typedef __attribute__((ext_vector_type(4))) float f32x4;
typedef __attribute__((ext_vector_type(4))) int i32x4;
typedef __attribute__((ext_vector_type(8))) int i32x8;
typedef __attribute__((ext_vector_type(8))) unsigned short u16x8;
typedef __attribute__((ext_vector_type(4))) unsigned short u16x4;

#define DI static __device__ __forceinline__

constexpr int CB = 8;          // batch (total)
constexpr int BCH = 4;         // batches per chunk (2 chunks)
constexpr int CC = 512;        // channels
constexpr int CN = 4096;       // H*W
constexpr int K1 = CC * 9;     // 4608
constexpr int MR = 3 * CC;     // 1536 output rows (q|k|v)
constexpr int KSPL = 8;        // QK^T split-K factor
constexpr size_t XSPLIT = (size_t)BCH * 66 * 66 * 512;

DI unsigned short f2bf(float f) {
  union { float f; uint32_t u; } v; v.f = f;
  uint32_t r = (v.u + 0x7FFFu + ((v.u >> 16) & 1u)) >> 16;  // RNE
  return (unsigned short)r;
}
DI float bf2f(unsigned short h) {
  union { uint32_t u; float f; } v; v.u = ((uint32_t)h) << 16;
  return v.f;
}
// manual OCP e4m3fn convert (RNE on mantissa; sat to 448); input |x| << 448 here
DI unsigned char f2e4m3(float x) {
  union { float f; uint32_t u; } v; v.f = x;
  uint32_t sgn = (v.u >> 24) & 0x80u;
  float a = fabsf(x);
  if (a < 0.015625f) {                       // subnormal: quantum 2^-9
    int qi = (int)rintf(a * 512.f);          // 0..8 (8 -> min normal 0x08)
    return (unsigned char)(sgn | (uint32_t)qi);
  }
  int e = (int)((v.u >> 23) & 0xff) - 127;
  uint32_t m3 = (v.u >> 20) & 7u;
  uint32_t rest = v.u & 0xFFFFFu;
  if (rest > 0x80000u || (rest == 0x80000u && (m3 & 1u))) {
    if (++m3 == 8u) { m3 = 0; ++e; }
  }
  if (e > 8 || (e == 8 && m3 == 7u)) return (unsigned char)(sgn | 0x7Eu);
  return (unsigned char)(sgn | ((uint32_t)(e + 7) << 3) | m3);
}

DI void g2lds16(const void* g, void* l) {
  __builtin_amdgcn_global_load_lds((const __attribute__((address_space(1))) void*)g,
                                   (__attribute__((address_space(3))) void*)l, 16, 0, 0);
}
#define SBAR()  __builtin_amdgcn_s_barrier()
#define SCHED() __builtin_amdgcn_sched_barrier(0)

// ---- prep 0: zero only the pad border cells --------------------------------
__global__ __launch_bounds__(256) void pad_zero(unsigned short* __restrict__ Xhi,
                                                unsigned char* __restrict__ X8) {
  int id = blockIdx.x * 256 + threadIdx.x;
  if (id >= 4 * 260 * 16) return;
  int t = id & 15;
  int pp = (id >> 4) % 260;
  int b = id / (260 * 16);
  int hh, ww;
  if (pp < 66)       { hh = 0;  ww = pp; }
  else if (pp < 132) { hh = 65; ww = pp - 66; }
  else if (pp < 196) { hh = pp - 131; ww = 0; }
  else               { hh = pp - 195; ww = 65; }
  size_t pix = (((size_t)b * 66 + hh) * 66 + ww) * 512 + (size_t)t * 32;
  const u16x8 z = {0, 0, 0, 0, 0, 0, 0, 0};
  *(u16x8*)&Xhi[pix] = z;  *(u16x8*)&Xhi[pix + 8] = z;
  *(u16x8*)&Xhi[pix + 16] = z;  *(u16x8*)&Xhi[pix + 24] = z;
  const i32x4 z4 = {0, 0, 0, 0};
  *(i32x4*)&X8[pix] = z4;  *(i32x4*)&X8[pix + 16] = z4;
  *(i32x4*)&X8[XSPLIT + pix] = z4;  *(i32x4*)&X8[XSPLIT + pix + 16] = z4;
}

// ---- prep 1: Xhi (bf16, x2^7), X8 split0=Xlo8 (x2^8), split1=Xhi8 (x1) -----
__global__ __launch_bounds__(256) void prep_xpad(const float* __restrict__ x,
                                                 unsigned short* __restrict__ Xhi,
                                                 unsigned char* __restrict__ X8) {
  int tid = threadIdx.x;
  int w = tid & 63;
  int ccl = tid >> 6;
  int blk = blockIdx.x;               // 4096 = b(4) * ccg(16) * h(64)
  int h = blk & 63;
  int ccg = (blk >> 6) & 15;
  int b = blk >> 10;
  int c0 = (ccg * 4 + ccl) * 8;
  const float* xp = x + ((size_t)b * CC) * CN + h * 64 + w;
  u16x8 hi;
  unsigned long long lo8 = 0, hi8 = 0;
#pragma unroll
  for (int j = 0; j < 8; ++j) {
    float v = xp[(size_t)(c0 + j) * CN];
    unsigned short h16 = f2bf(v);
    float vhi = bf2f(h16);
    hi[j] = f2bf(vhi * 128.f);                    // exact shift
    lo8 |= (unsigned long long)f2e4m3((v - vhi) * 256.f) << (8 * j);
    hi8 |= (unsigned long long)f2e4m3(vhi) << (8 * j);
  }
  size_t pix = (((size_t)b * 66 + (h + 1)) * 66 + (w + 1)) * 512;
  *(u16x8*)&Xhi[pix + c0] = hi;
  *(unsigned long long*)&X8[pix + c0] = lo8;
  *(unsigned long long*)&X8[XSPLIT + pix + c0] = hi8;
}

// ---- prep 2: Ahi [1536][4608] bf16 (x2^7), A8 [1536][9216] fp8 plain -------
__global__ __launch_bounds__(256) void prep_abig(
    const float* __restrict__ wq, const float* __restrict__ wk,
    const float* __restrict__ wv, const float* __restrict__ bq,
    const float* __restrict__ bk, const float* __restrict__ bv,
    unsigned short* __restrict__ Ahi, unsigned char* __restrict__ A8,
    float* __restrict__ bias) {
  unsigned id = blockIdx.x * 256 + threadIdx.x;   // total 1536*4608
  int m = id / K1;
  int r = id - m * K1;
  int t = r >> 9;
  int c = r & 511;
  int ky = t / 3;
  int kx = t - ky * 3;
  size_t ip = (size_t)m * 9216 + r;
  if (m < 1024) {
    const float* wp = (m < 512) ? wq : wk;
    int mm = (m < 512) ? m : m - 512;
    float wval = wp[(((size_t)mm * 512 + c) * 3 + ky) * 3 + kx];
    float whi = bf2f(f2bf(wval));
    Ahi[id] = f2bf(whi * 128.f);
    A8[ip] = f2e4m3(whi * 64.f);
    A8[ip + 4608] = f2e4m3((wval - whi) * 16384.f);
  } else {
    float wval = wv[(((size_t)(m - 1024) * 512 + c) * 3 + ky) * 3 + kx];
    Ahi[id] = f2bf(wval * 128.f);
    A8[ip] = 0;
    A8[ip + 4608] = 0;
  }
  if (id < 1536) {
    int mm = (int)id;
    bias[mm] = (mm < 512) ? bq[mm] : (mm < 1024) ? bk[mm - 512] : bv[mm - 1024];
  }
}

// ---- conv GEMM r16: 128x256 tiles, 3-slot ring (72KB), 2 blocks/CU ---------
// All blocks (heavy q/k AND light v) run the SAME phase-1 loop: 128-row A,
// 3 loads/stage, vmcnt(3), r9-proven 2-barrier body. Heavy blocks append the
// scaled-fp8 K=128 phase 2 as serial slot-pairs {0,1} with a full drain per
// pair -- the exposed latency is covered by the OTHER resident block (m114
// cross-block overlap; the point of this round). acc[4][4], ~100 VGPR,
// launch_bounds(512,4) -> 16 waves/CU (vs 8).
__global__ __launch_bounds__(512, 4) void conv_k(
    const unsigned short* __restrict__ Ahi,
    const unsigned char* __restrict__ A8,
    const unsigned short* __restrict__ Xhi,
    const unsigned char* __restrict__ X8,
    const float* __restrict__ bias,
    unsigned short* __restrict__ Qhi, unsigned short* __restrict__ Qlo,
    unsigned short* __restrict__ Khi, unsigned short* __restrict__ Klo,
    unsigned short* __restrict__ Vt)
{
  __shared__ __align__(16) unsigned char smem[3 * 24576];   // 72 KB
  const int tid = threadIdx.x;
  const int lane = tid & 63;
  const int wid = tid >> 6;
  const int wr = wid >> 2;            // 0..1 (M): 64-row halves of 128
  const int wc = wid & 3;             // 0..3 (N): 64-col quarters of 256

  // XCD-local mapping: xcd = id&7 owns nb panels [8x,8x+8). Heavy (512) first
  // -> 2 per CU; light (256) backfills.
  int orig = blockIdx.x;
  int xcd, nbl, m0;
  if (orig < 512) {                   // heavy q/k: 128x256, m-slices 0..7
    xcd = orig & 7; int j = orig >> 3;        // 0..63
    nbl = j >> 3;
    m0 = (j & 7) * 128;               // 0..896
  } else {                            // light v: 128x256, m-slices 0..3
    int o = orig - 512;
    xcd = o & 7; int j = o >> 3;      // 0..31
    nbl = j >> 2;
    m0 = 1024 + (j & 3) * 128;        // 1024..1408
  }
  const int nb = xcd * 8 + nbl;
  const int n0 = nb * 256;
  const int bidx = n0 >> 12;
  const int nl0 = n0 & (CN - 1);
  const int h0 = nl0 >> 6;

  // per-thread staging bases; source chunk pre-swizzled by f(srow)
  const int srow = tid >> 2;          // 0..127
  const int scu = tid & 3;
  const int scuS = scu ^ ((srow >> 1) & 3);
  const size_t pixOfs = (((size_t)(bidx * 66 + h0 + (srow >> 6))) * 66 + (srow & 63)) * 512;
  const unsigned short* gAh0 = Ahi + (size_t)(m0 + srow) * K1 + scuS * 8;
  const unsigned short* gBh0 = Xhi + pixOfs + scuS * 8;
  const unsigned short* gBh1 = gBh0 + (size_t)2 * 66 * 512;
  const unsigned char* gA80 = A8 + (size_t)(m0 + srow) * 9216 + scuS * 16;
  const unsigned char* gB80 = X8 + pixOfs + scuS * 16;
  const unsigned char* gB81 = gB80 + (size_t)2 * 66 * 512;
  const int wofs = wid * 1024;

  // phase-1 cursor (s0 bf16: tap 0..8 x c0 step 32 -> 144 ktiles)
  int c0S = 0, kxS = 0, tapS = 0;
  size_t tapOfs = 0;
  auto stage1 = [&](int slot) {       // 3 loads: A 8KB, B 2x8KB
    int aOfs = tapS * 512 + c0S;
    size_t bOfs = tapOfs + (size_t)c0S;
    unsigned char* lS = smem + slot * 24576 + wofs;
    g2lds16(gAh0 + aOfs, lS);
    g2lds16(gBh0 + bOfs, lS + 8192);
    g2lds16(gBh1 + bOfs, lS + 16384);
    c0S += 32;
    if (c0S == 512) {
      c0S = 0; ++tapS;
      if (kxS == 2) { kxS = 0; tapOfs += (size_t)64 * 512; }
      else { ++kxS; tapOfs += 512; }
    }
  };
  // phase-2 cursor (fp8: s' 0..1 x tap 0..8 x c step 128 -> 72 pairs)
  int c2 = 0, kx2 = 0, tap2 = 0, s2 = 0;
  size_t tapOfs2 = 0;
  auto stagePair = [&]() {            // slot0 = k-half c2, slot1 = c2+64
    int aOfs = s2 * 4608 + tap2 * 512 + c2;
    size_t bOfs = (size_t)s2 * XSPLIT + tapOfs2 + (size_t)c2;
    g2lds16(gA80 + aOfs, smem + wofs);
    g2lds16(gB80 + bOfs, smem + 8192 + wofs);
    g2lds16(gB81 + bOfs, smem + 16384 + wofs);
    g2lds16(gA80 + aOfs + 64, smem + 24576 + wofs);
    g2lds16(gB80 + bOfs + 64, smem + 24576 + 8192 + wofs);
    g2lds16(gB81 + bOfs + 64, smem + 24576 + 16384 + wofs);
    c2 += 128;
    if (c2 == 512) {
      c2 = 0; ++tap2;
      if (tap2 == 9) { tap2 = 0; kx2 = 0; tapOfs2 = 0; ++s2; }
      else if (kx2 == 2) { kx2 = 0; tapOfs2 += (size_t)64 * 512; }
      else { ++kx2; tapOfs2 += 512; }
    }
  };

  f32x4 acc[4][4];
  const f32x4 fz = {0.f, 0.f, 0.f, 0.f};
#pragma unroll
  for (int i = 0; i < 4; ++i)
#pragma unroll
    for (int j = 0; j < 4; ++j) acc[i][j] = fz;

  const int rAv = wr * 64 + (lane & 15);     // A rows 0..127
  const int rB = wc * 64 + (lane & 15);      // B rows 0..255
  const int kq = (lane >> 4) * 16;
  const int kqA = kq ^ (((rAv >> 1) & 3) << 4);   // r7 swizzle (0-conflict)
  const int kqB = kq ^ (((rB >> 1) & 3) << 4);

  // ================= phase 1 (ALL blocks): bf16 s0, 144 ktiles =============
  stage1(0);
  stage1(1);
  asm volatile("s_waitcnt vmcnt(3)" ::: "memory");
  SCHED(); SBAR(); SCHED();
  {
    bf16x8 afA[4], bfA[4], afB[4], bfB[4];
#pragma unroll
    for (int mf = 0; mf < 4; ++mf)
      afA[mf] = *(const bf16x8*)(smem + (rAv + mf * 16) * 64 + kqA);
#pragma unroll
    for (int nf = 0; nf < 4; ++nf)
      bfA[nf] = *(const bf16x8*)(smem + 8192 + (rB + nf * 16) * 64 + kqB);
    int slotC = 0, slotS = 2, t2 = 2;

#define CONV_P1(CURA, CURB, NXTA, NXTB)                                       \
  {                                                                           \
    if (t2 < 144) {                                                           \
      stage1(slotS); slotS = (slotS == 2) ? 0 : slotS + 1;                    \
      asm volatile("s_waitcnt vmcnt(3)" ::: "memory");                        \
    } else {                                                                  \
      asm volatile("s_waitcnt vmcnt(0)" ::: "memory");                        \
    }                                                                         \
    SCHED(); SBAR(); SCHED();                                                 \
    const int slotN = (slotC == 2) ? 0 : slotC + 1;                           \
    const unsigned char* lAn = smem + slotN * 24576;                          \
    _Pragma("unroll")                                                         \
    for (int mf = 0; mf < 4; ++mf)                                            \
      NXTA[mf] = *(const bf16x8*)(lAn + (rAv + mf * 16) * 64 + kqA);          \
    _Pragma("unroll")                                                         \
    for (int nf = 0; nf < 4; ++nf)                                            \
      NXTB[nf] = *(const bf16x8*)(lAn + 8192 + (rB + nf * 16) * 64 + kqB);    \
    __builtin_amdgcn_s_setprio(1);                                            \
    _Pragma("unroll")                                                         \
    for (int mf = 0; mf < 4; ++mf) {                                          \
      _Pragma("unroll")                                                       \
      for (int nf = 0; nf < 4; ++nf)                                          \
        acc[mf][nf] = __builtin_amdgcn_mfma_f32_16x16x32_bf16(                \
            CURA[mf], CURB[nf], acc[mf][nf], 0, 0, 0);                        \
    }                                                                         \
    __builtin_amdgcn_s_setprio(0);                                            \
    asm volatile("s_waitcnt lgkmcnt(0)" ::: "memory");                        \
    SCHED(); SBAR(); SCHED();                                                 \
    slotC = slotN;                                                            \
    ++t2;                                                                     \
  }

    for (int t = 0; t < 144; t += 2) {
      CONV_P1(afA, bfA, afB, bfB)
      CONV_P1(afB, bfB, afA, bfA)
    }
#undef CONV_P1
  }

  // ================= phase 2 (heavy only): scaled fp8, 72 serial pairs =====
  if (m0 < 1024) {
    const int gq = lane >> 4;                  // k-quarter 0..3
    const int slotByte = (gq >> 1) * 24576;    // pair slot (k-half)
    const int cb2 = (gq & 1) * 2;              // 16B chunk base in 64B row
    const int fx = ((lane & 15) >> 1) & 3;     // swizzle f(row), +16-invariant
    const int bo0 = ((cb2 ^ fx) << 4);
    const int bo1 = (((cb2 + 1) ^ fx) << 4);
    i32x8 aF[4], bF[4];
    for (int p = 0; p < 72; ++p) {
      stagePair();                             // 6 loads into slots 0,1
      asm volatile("s_waitcnt vmcnt(0)" ::: "memory");
      SCHED(); SBAR(); SCHED();
      const unsigned char* pbA = smem + slotByte;
      const unsigned char* pbB = smem + slotByte + 8192;
#pragma unroll
      for (int s = 0; s < 4; ++s) {
        const unsigned char* ra = pbA + (rAv + s * 16) * 64;
        *(i32x4*)&aF[s] = *(const i32x4*)(ra + bo0);
        *((i32x4*)&aF[s] + 1) = *(const i32x4*)(ra + bo1);
      }
#pragma unroll
      for (int tt = 0; tt < 4; ++tt) {
        const unsigned char* rb = pbB + (rB + tt * 16) * 64;
        *(i32x4*)&bF[tt] = *(const i32x4*)(rb + bo0);
        *((i32x4*)&bF[tt] + 1) = *(const i32x4*)(rb + bo1);
      }
      __builtin_amdgcn_s_setprio(1);
#pragma unroll
      for (int s = 0; s < 4; ++s)
#pragma unroll
        for (int tt = 0; tt < 4; ++tt)
          acc[s][tt] = __builtin_amdgcn_mfma_scale_f32_16x16x128_f8f6f4(
              aF[s], bF[tt], acc[s][tt], 0, 0, 0, 127, 0, 127);
      __builtin_amdgcn_s_setprio(0);
      SCHED(); SBAR(); SCHED();                // reads done -> restage safe
    }
  }

  // ---- epilogue: all products at scale 2^14 -> * 2^-14 ----
  constexpr float SC = 1.f / 16384.f;
#pragma unroll
  for (int mf = 0; mf < 4; ++mf) {
#pragma unroll
    for (int nf = 0; nf < 4; ++nf) {
      f32x4 a = acc[mf][nf];
      int mrow = m0 + wr * 64 + mf * 16 + ((lane >> 4) << 2);
      int ncol = nl0 + wc * 64 + nf * 16 + (lane & 15);
      if (m0 < 512) {
#pragma unroll
        for (int j = 0; j < 4; ++j) {
          float v = a[j] * SC + bias[mrow + j];
          unsigned short h16 = f2bf(v);
          size_t o = ((size_t)bidx * CC + (mrow + j)) * CN + ncol;
          Qhi[o] = h16;
          Qlo[o] = f2bf(v - bf2f(h16));
        }
      } else if (m0 < 1024) {
#pragma unroll
        for (int j = 0; j < 4; ++j) {
          float v = a[j] * SC + bias[mrow + j];
          unsigned short h16 = f2bf(v);
          size_t o = ((size_t)bidx * CC + (mrow + j - 512)) * CN + ncol;
          Khi[o] = h16;
          Klo[o] = f2bf(v - bf2f(h16));
        }
      } else {
        u16x4 vs;                     // V written transposed: Vt[b][n][d]
#pragma unroll
        for (int j = 0; j < 4; ++j) vs[j] = f2bf(a[j] * SC + bias[mrow + j]);
        *(u16x4*)&Vt[((size_t)bidx * CN + ncol) * CC + (mrow - 1024)] = vs;
      }
    }
  }
}

// ---- QK^T: 4-slot/1-barrier template (r14, unchanged) ----------------------
__global__ __launch_bounds__(512, 2) void qk_k(
    const unsigned short* __restrict__ Qhi, const unsigned short* __restrict__ Qlo,
    const unsigned short* __restrict__ Khi, const unsigned short* __restrict__ Klo,
    float* __restrict__ attn)
{
  __shared__ __align__(16) unsigned char smem[4 * 24576];
  const int tid = threadIdx.x;
  const int lane = tid & 63;
  const int wid = tid >> 6;
  const int wr = wid >> 2;
  const int wc = wid & 3;

  int orig = blockIdx.x;              // 0..63
  int work = (orig & 7) * 8 + (orig >> 3);
  const int mt = work & 3;
  const int nt = (work >> 2) & 1;
  const int ks = work >> 3;           // 0..7
  const int bidx = blockIdx.z;
  const int m0 = mt * 128;
  const int n0 = nt * 256;

  const int srow = tid >> 2;
  const int scu = tid & 3;
  const int scuS = scu ^ ((srow >> 1) & 3);
  const size_t rowA = ((size_t)bidx * CC + m0 + srow) * CN + scuS * 8;
  const size_t rowB = ((size_t)bidx * CC + n0 + srow) * CN + scuS * 8;
  const size_t rowB2 = rowB + (size_t)128 * CN;
  const int wofs = wid * 1024;

  int kk = ks * 1536;
  auto stageQ = [&](int slot) {
    int ph = kk >> 12;
    int kin = kk & (CN - 1);
    const unsigned short* Aq = (ph == 2) ? Qlo : Qhi;
    const unsigned short* Bk = (ph == 1) ? Klo : Khi;
    unsigned char* lA = smem + slot * 24576 + wofs;
    unsigned char* lB = smem + slot * 24576 + 8192 + wofs;
    g2lds16(Aq + rowA + kin, lA);
    g2lds16(Bk + rowB + kin, lB);
    g2lds16(Bk + rowB2 + kin, lB + 8192);
    kk += 32;
  };

  f32x4 acc[4][4];
  const f32x4 fz = {0.f, 0.f, 0.f, 0.f};
#pragma unroll
  for (int i = 0; i < 4; ++i)
#pragma unroll
    for (int j = 0; j < 4; ++j) acc[i][j] = fz;

  const int rAv = wr * 64 + (lane & 15);
  const int rB = wc * 64 + (lane & 15);
  const int kq = (lane >> 4) * 16;
  const int kqA = kq ^ (((rAv >> 1) & 3) << 4);
  const int kqB = kq ^ (((rB >> 1) & 3) << 4);

  stageQ(0);
  stageQ(1);
  asm volatile("s_waitcnt vmcnt(3)" ::: "memory");
  SCHED(); SBAR(); SCHED();
  bf16x8 afA[4], bfA[4], afB[4], bfB[4];
#pragma unroll
  for (int mf = 0; mf < 4; ++mf)
    afA[mf] = *(const bf16x8*)(smem + (rAv + mf * 16) * 64 + kqA);
#pragma unroll
  for (int nf = 0; nf < 4; ++nf)
    bfA[nf] = *(const bf16x8*)(smem + 8192 + (rB + nf * 16) * 64 + kqB);
  int slotC = 0, slotS = 2, t2 = 2;

#define QK_BODY(CURA, CURB, NXTA, NXTB)                                       \
  {                                                                           \
    if (t2 < 48) {                                                            \
      stageQ(slotS); slotS = (slotS + 1) & 3;                                 \
      asm volatile("s_waitcnt vmcnt(3)" ::: "memory");                        \
    } else {                                                                  \
      asm volatile("s_waitcnt vmcnt(0)" ::: "memory");                        \
    }                                                                         \
    SCHED(); SBAR(); SCHED();                                                 \
    const int slotN = (slotC + 1) & 3;                                        \
    const unsigned char* lAn = smem + slotN * 24576;                          \
    _Pragma("unroll")                                                         \
    for (int mf = 0; mf < 4; ++mf)                                            \
      NXTA[mf] = *(const bf16x8*)(lAn + (rAv + mf * 16) * 64 + kqA);          \
    _Pragma("unroll")                                                         \
    for (int nf = 0; nf < 4; ++nf)                                            \
      NXTB[nf] = *(const bf16x8*)(lAn + 8192 + (rB + nf * 16) * 64 + kqB);    \
    __builtin_amdgcn_s_setprio(1);                                            \
    _Pragma("unroll")                                                         \
    for (int mf = 0; mf < 4; ++mf) {                                          \
      _Pragma("unroll")                                                       \
      for (int nf = 0; nf < 4; ++nf)                                          \
        acc[mf][nf] = __builtin_amdgcn_mfma_f32_16x16x32_bf16(                \
            CURA[mf], CURB[nf], acc[mf][nf], 0, 0, 0);                        \
    }                                                                         \
    __builtin_amdgcn_s_setprio(0);                                            \
    slotC = slotN;                                                            \
    ++t2;                                                                     \
  }

  for (int t = 0; t < 48; t += 2) {
    QK_BODY(afA, bfA, afB, bfB)
    QK_BODY(afB, bfB, afA, bfA)
  }
#undef QK_BODY

  size_t pbase = (size_t)ks * ((size_t)BCH * CC * CC);
#pragma unroll
  for (int mf = 0; mf < 4; ++mf) {
#pragma unroll
    for (int nf = 0; nf < 4; ++nf) {
      f32x4 a = acc[mf][nf];
      int mrow = m0 + wr * 64 + mf * 16 + ((lane >> 4) << 2);
      int ncol = n0 + wc * 64 + nf * 16 + (lane & 15);
#pragma unroll
      for (int j = 0; j < 4; ++j)
        attn[pbase + ((size_t)bidx * CC + (mrow + j)) * CC + ncol] = a[j];
    }
  }
}

// ---- PV GEMM (unchanged) ---------------------------------------------------
DI int sofs(int row, int kb) { return row * 128 + (kb ^ ((row & 7) << 4)); }

__global__ __launch_bounds__(256) void pv_k(
    const unsigned short* __restrict__ Vt,
    const unsigned short* __restrict__ P,
    const float* __restrict__ xin,
    const float* __restrict__ gamma,
    float* __restrict__ out)
{
  __shared__ __align__(16) unsigned char sA[16384];
  __shared__ __align__(16) unsigned char sB[16384];
  const int tid = threadIdx.x;
  const int lane = tid & 63;
  const int wav = tid >> 6;
  const int wr = wav >> 1, wc = wav & 1;

  const int m0 = (blockIdx.x & 3) * 128;
  const int n0 = (blockIdx.x >> 2) * 128;
  const int bidx = blockIdx.z;

  auto stage = [&](int k0) {
#pragma unroll
    for (int q = 0; q < 4; ++q) {
      int ci = q * 256 + tid;
      int row = ci >> 3;
      int ke = ((ci & 7) ^ (row & 7)) * 8;
      const unsigned short* ap = P + ((size_t)bidx * CC + (m0 + row)) * CC + (k0 + ke);
      const unsigned short* bp = Vt + ((size_t)bidx * CN + (n0 + row)) * CC + (k0 + ke);
      int wbase = (q * 256 + wav * 64) * 16;
      g2lds16(ap, sA + wbase);
      g2lds16(bp, sB + wbase);
    }
  };

  f32x4 acc[4][4];
  const f32x4 fz = {0.f, 0.f, 0.f, 0.f};
#pragma unroll
  for (int i = 0; i < 4; ++i)
#pragma unroll
    for (int j = 0; j < 4; ++j) acc[i][j] = fz;

  for (int k0 = 0; k0 < CC; k0 += 64) {
    stage(k0);
    __syncthreads();
#pragma unroll
    for (int kkp = 0; kkp < 2; ++kkp) {
      bf16x8 af[4], bfv[4];
#pragma unroll
      for (int mf = 0; mf < 4; ++mf)
        af[mf] = *(const bf16x8*)&sA[sofs(wr * 64 + mf * 16 + (lane & 15),
                                          kkp * 64 + (lane >> 4) * 16)];
#pragma unroll
      for (int nf = 0; nf < 4; ++nf)
        bfv[nf] = *(const bf16x8*)&sB[sofs(wc * 64 + nf * 16 + (lane & 15),
                                           kkp * 64 + (lane >> 4) * 16)];
#pragma unroll
      for (int mf = 0; mf < 4; ++mf)
#pragma unroll
        for (int nf = 0; nf < 4; ++nf)
          acc[mf][nf] = __builtin_amdgcn_mfma_f32_16x16x32_bf16(
              af[mf], bfv[nf], acc[mf][nf], 0, 0, 0);
    }
    __syncthreads();
  }

  float g = gamma[0];
#pragma unroll
  for (int mf = 0; mf < 4; ++mf) {
#pragma unroll
    for (int nf = 0; nf < 4; ++nf) {
      f32x4 a = acc[mf][nf];
      int mrow = m0 + wr * 64 + mf * 16 + ((lane >> 4) << 2);
      int ncol = n0 + wc * 64 + nf * 16 + (lane & 15);
#pragma unroll
      for (int j = 0; j < 4; ++j) {
        size_t o = ((size_t)bidx * CC + (mrow + j)) * CN + ncol;
        out[o] = g * a[j] + xin[o];
      }
    }
  }
}

// ---- softmax over d (512): sum KSPL split-K partials, one wave per row -----
__global__ __launch_bounds__(256) void softmax_k(const float* __restrict__ attn,
                                                 unsigned short* __restrict__ P) {
  int row = blockIdx.x * 4 + (threadIdx.x >> 6);
  int lane = threadIdx.x & 63;
  constexpr size_t PS = (size_t)BCH * CC * CC;
  const float* rp = attn + (size_t)row * 512 + lane * 8;
  f32x4 a = {0.f, 0.f, 0.f, 0.f};
  f32x4 b = {0.f, 0.f, 0.f, 0.f};
#pragma unroll
  for (int ksp = 0; ksp < KSPL; ++ksp) {
    a += *(const f32x4*)(rp + (size_t)ksp * PS);
    b += *(const f32x4*)(rp + (size_t)ksp * PS + 4);
  }
  float mx = fmaxf(fmaxf(fmaxf(a[0], a[1]), fmaxf(a[2], a[3])),
                   fmaxf(fmaxf(b[0], b[1]), fmaxf(b[2], b[3])));
#pragma unroll
  for (int s = 32; s > 0; s >>= 1) mx = fmaxf(mx, __shfl_xor(mx, s, 64));
  float e[8];
  float sum = 0.f;
#pragma unroll
  for (int j = 0; j < 4; ++j) { e[j] = __expf(a[j] - mx); sum += e[j]; }
#pragma unroll
  for (int j = 0; j < 4; ++j) { e[4 + j] = __expf(b[j] - mx); sum += e[4 + j]; }
#pragma unroll
  for (int s = 32; s > 0; s >>= 1) sum += __shfl_xor(sum, s, 64);
  float inv = 1.0f / sum;
  u16x8 o;
#pragma unroll
  for (int j = 0; j < 8; ++j) o[j] = f2bf(e[j] * inv);
  *(u16x8*)&P[(size_t)row * 512 + lane * 8] = o;
}

// ---- diagnostic: fill out with sentinel if workspace is too small ----------
__global__ __launch_bounds__(256) void fill_sentinel(float* __restrict__ out, int n) {
  int i = blockIdx.x * 256 + threadIdx.x;
  if (i < n) out[i] = 1.0e4f;
}

// ---------------------------------------------------------------------------
extern "C" void kernel_launch(void* const* d_in, const int* in_sizes, int n_in,
                              void* d_out, int out_size, void* d_ws, size_t ws_size,
                              hipStream_t stream) {
  (void)in_sizes; (void)n_in;
  const float* x  = (const float*)d_in[0];
  const float* wq = (const float*)d_in[1];
  const float* bq = (const float*)d_in[2];
  const float* wk = (const float*)d_in[3];
  const float* bk = (const float*)d_in[4];
  const float* wv = (const float*)d_in[5];
  const float* bv = (const float*)d_in[6];
  const float* gm = (const float*)d_in[7];
  float* out = (float*)d_out;

  uint8_t* wsp = (uint8_t*)d_ws;
  auto take = [&](size_t bytes) {
    uint8_t* p = wsp;
    wsp += (bytes + 255) & ~(size_t)255;
    return p;
  };
  unsigned short* Xhi = (unsigned short*)take(XSPLIT * 2);          // 17.8 MB
  unsigned char*  X8  = (unsigned char*)take(2 * XSPLIT);           // 35.7 MB
  unsigned short* Ahi = (unsigned short*)take((size_t)MR * K1 * 2); // 13.5 MB
  unsigned char*  A8  = (unsigned char*)take((size_t)MR * 2 * K1);  // 13.5 MB
  float* bias         = (float*)take((size_t)MR * 4);
  unsigned short* Khi = (unsigned short*)take((size_t)BCH * CC * CN * 2);  // 16.8 MB
  unsigned short* Klo = (unsigned short*)take((size_t)BCH * CC * CN * 2);  // 16.8 MB
  unsigned short* Vt  = (unsigned short*)take((size_t)BCH * CN * CC * 2);  // 16.8 MB
  float* attn         = (float*)Xhi;
  unsigned short* P   = (unsigned short*)((uint8_t*)Xhi +
                          (size_t)KSPL * BCH * CC * CC * 4 + 256);

  size_t needed = (size_t)(wsp - (uint8_t*)d_ws);   // ~113 MB
  if (ws_size < needed) {
    fill_sentinel<<<(out_size + 255) / 256, 256, 0, stream>>>(out, out_size);
    return;
  }

  for (int ch = 0; ch < CB / BCH; ++ch) {
    const float* xch = x + (size_t)ch * BCH * CC * CN;
    float* outch = out + (size_t)ch * BCH * CC * CN;
    unsigned short* Qhi = (unsigned short*)outch;   // Q pair lives in d_out
    unsigned short* Qlo = Qhi + (size_t)BCH * CC * CN;

    pad_zero<<<(4 * 260 * 16 + 255) / 256, 256, 0, stream>>>(Xhi, X8);
    prep_xpad<<<BCH * 16 * 64, 256, 0, stream>>>(xch, Xhi, X8);
    if (ch == 0)
      prep_abig<<<(MR * K1) / 256, 256, 0, stream>>>(wq, wk, wv, bq, bk, bv,
                                                     Ahi, A8, bias);
    conv_k<<<dim3(768), 512, 0, stream>>>(Ahi, A8, Xhi, X8, bias,
                                          Qhi, Qlo, Khi, Klo, Vt);
    qk_k<<<dim3(64, 1, BCH), 512, 0, stream>>>(Qhi, Qlo, Khi, Klo, attn);
    softmax_k<<<BCH * 128, 256, 0, stream>>>(attn, P);
    pv_k<<<dim3(128, 1, BCH), 256, 0, stream>>>(Vt, P, xch, gm, outch);
  }
}

// Round 17
// 940.152 us; speedup vs baseline: 2.5631x; 2.5631x over previous
//
#include <hip/hip_runtime.h>
#include <stdint.h>

typedef __attribute__((ext_vector_type(8))) short bf16x8;
typedef __attribute__((ext_vector_type(4))) float f32x4;
typedef __attribute__((ext_vector_type(4))) int i32x4;
typedef __attribute__((ext_vector_type(8))) int i32x8;
typedef __attribute__((ext_vector_type(8))) unsigned short u16x8;
typedef __attribute__((ext_vector_type(4))) unsigned short u16x4;

#define DI static __device__ __forceinline__

constexpr int CB = 8;          // batch (total)
constexpr int BCH = 4;         // batches per chunk (2 chunks)
constexpr int CC = 512;        // channels
constexpr int CN = 4096;       // H*W
constexpr int K1 = CC * 9;     // 4608
constexpr int MR = 3 * CC;     // 1536 output rows (q|k|v)
constexpr int KSPL = 8;        // QK^T split-K factor
constexpr size_t XSPLIT = (size_t)BCH * 66 * 66 * 512;

DI unsigned short f2bf(float f) {
  union { float f; uint32_t u; } v; v.f = f;
  uint32_t r = (v.u + 0x7FFFu + ((v.u >> 16) & 1u)) >> 16;  // RNE
  return (unsigned short)r;
}
DI float bf2f(unsigned short h) {
  union { uint32_t u; float f; } v; v.u = ((uint32_t)h) << 16;
  return v.f;
}
// manual OCP e4m3fn convert (RNE on mantissa; sat to 448); input |x| << 448 here
DI unsigned char f2e4m3(float x) {
  union { float f; uint32_t u; } v; v.f = x;
  uint32_t sgn = (v.u >> 24) & 0x80u;
  float a = fabsf(x);
  if (a < 0.015625f) {                       // subnormal: quantum 2^-9
    int qi = (int)rintf(a * 512.f);          // 0..8 (8 -> min normal 0x08)
    return (unsigned char)(sgn | (uint32_t)qi);
  }
  int e = (int)((v.u >> 23) & 0xff) - 127;
  uint32_t m3 = (v.u >> 20) & 7u;
  uint32_t rest = v.u & 0xFFFFFu;
  if (rest > 0x80000u || (rest == 0x80000u && (m3 & 1u))) {
    if (++m3 == 8u) { m3 = 0; ++e; }
  }
  if (e > 8 || (e == 8 && m3 == 7u)) return (unsigned char)(sgn | 0x7Eu);
  return (unsigned char)(sgn | ((uint32_t)(e + 7) << 3) | m3);
}

DI void g2lds16(const void* g, void* l) {
  __builtin_amdgcn_global_load_lds((const __attribute__((address_space(1))) void*)g,
                                   (__attribute__((address_space(3))) void*)l, 16, 0, 0);
}
#define SBAR()  __builtin_amdgcn_s_barrier()
#define SCHED() __builtin_amdgcn_sched_barrier(0)

// ---- prep 0: zero only the pad border cells --------------------------------
__global__ __launch_bounds__(256) void pad_zero(unsigned short* __restrict__ Xhi,
                                                unsigned char* __restrict__ X8) {
  int id = blockIdx.x * 256 + threadIdx.x;
  if (id >= 4 * 260 * 16) return;
  int t = id & 15;
  int pp = (id >> 4) % 260;
  int b = id / (260 * 16);
  int hh, ww;
  if (pp < 66)       { hh = 0;  ww = pp; }
  else if (pp < 132) { hh = 65; ww = pp - 66; }
  else if (pp < 196) { hh = pp - 131; ww = 0; }
  else               { hh = pp - 195; ww = 65; }
  size_t pix = (((size_t)b * 66 + hh) * 66 + ww) * 512 + (size_t)t * 32;
  const u16x8 z = {0, 0, 0, 0, 0, 0, 0, 0};
  *(u16x8*)&Xhi[pix] = z;  *(u16x8*)&Xhi[pix + 8] = z;
  *(u16x8*)&Xhi[pix + 16] = z;  *(u16x8*)&Xhi[pix + 24] = z;
  const i32x4 z4 = {0, 0, 0, 0};
  *(i32x4*)&X8[pix] = z4;  *(i32x4*)&X8[pix + 16] = z4;
  *(i32x4*)&X8[XSPLIT + pix] = z4;  *(i32x4*)&X8[XSPLIT + pix + 16] = z4;
}

// ---- prep 1: Xhi (bf16, x2^7), X8 split0=Xlo8 (x2^8), split1=Xhi8 (x1) -----
__global__ __launch_bounds__(256) void prep_xpad(const float* __restrict__ x,
                                                 unsigned short* __restrict__ Xhi,
                                                 unsigned char* __restrict__ X8) {
  int tid = threadIdx.x;
  int w = tid & 63;
  int ccl = tid >> 6;
  int blk = blockIdx.x;               // 4096 = b(4) * ccg(16) * h(64)
  int h = blk & 63;
  int ccg = (blk >> 6) & 15;
  int b = blk >> 10;
  int c0 = (ccg * 4 + ccl) * 8;
  const float* xp = x + ((size_t)b * CC) * CN + h * 64 + w;
  u16x8 hi;
  unsigned long long lo8 = 0, hi8 = 0;
#pragma unroll
  for (int j = 0; j < 8; ++j) {
    float v = xp[(size_t)(c0 + j) * CN];
    unsigned short h16 = f2bf(v);
    float vhi = bf2f(h16);
    hi[j] = f2bf(vhi * 128.f);                    // exact shift
    lo8 |= (unsigned long long)f2e4m3((v - vhi) * 256.f) << (8 * j);
    hi8 |= (unsigned long long)f2e4m3(vhi) << (8 * j);
  }
  size_t pix = (((size_t)b * 66 + (h + 1)) * 66 + (w + 1)) * 512;
  *(u16x8*)&Xhi[pix + c0] = hi;
  *(unsigned long long*)&X8[pix + c0] = lo8;
  *(unsigned long long*)&X8[XSPLIT + pix + c0] = hi8;
}

// ---- prep 2: Ahi [1536][4608] bf16 (x2^7), A8 [1536][9216] fp8 plain -------
__global__ __launch_bounds__(256) void prep_abig(
    const float* __restrict__ wq, const float* __restrict__ wk,
    const float* __restrict__ wv, const float* __restrict__ bq,
    const float* __restrict__ bk, const float* __restrict__ bv,
    unsigned short* __restrict__ Ahi, unsigned char* __restrict__ A8,
    float* __restrict__ bias) {
  unsigned id = blockIdx.x * 256 + threadIdx.x;   // total 1536*4608
  int m = id / K1;
  int r = id - m * K1;
  int t = r >> 9;
  int c = r & 511;
  int ky = t / 3;
  int kx = t - ky * 3;
  size_t ip = (size_t)m * 9216 + r;
  if (m < 1024) {
    const float* wp = (m < 512) ? wq : wk;
    int mm = (m < 512) ? m : m - 512;
    float wval = wp[(((size_t)mm * 512 + c) * 3 + ky) * 3 + kx];
    float whi = bf2f(f2bf(wval));
    Ahi[id] = f2bf(whi * 128.f);
    A8[ip] = f2e4m3(whi * 64.f);
    A8[ip + 4608] = f2e4m3((wval - whi) * 16384.f);
  } else {
    float wval = wv[(((size_t)(m - 1024) * 512 + c) * 3 + ky) * 3 + kx];
    Ahi[id] = f2bf(wval * 128.f);
    A8[ip] = 0;
    A8[ip + 4608] = 0;
  }
  if (id < 1536) {
    int mm = (int)id;
    bias[mm] = (mm < 512) ? bq[mm] : (mm < 1024) ? bk[mm - 512] : bv[mm - 1024];
  }
}

// ---- conv GEMM: r15 structure VERBATIM (r16's 2-blocks/CU spilled: VGPR
// ledger 160 > 128 cap -> 1.16GB scratch writes; reverted) -------------------
__global__ __launch_bounds__(512, 2) void conv_k(
    const unsigned short* __restrict__ Ahi,
    const unsigned char* __restrict__ A8,
    const unsigned short* __restrict__ Xhi,
    const unsigned char* __restrict__ X8,
    const float* __restrict__ bias,
    unsigned short* __restrict__ Qhi, unsigned short* __restrict__ Qlo,
    unsigned short* __restrict__ Khi, unsigned short* __restrict__ Klo,
    unsigned short* __restrict__ Vt)
{
  __shared__ __align__(16) unsigned char smem[4 * 32768];
  const int tid = threadIdx.x;
  const int lane = tid & 63;
  const int wid = tid >> 6;
  const int wr = wid >> 2;            // 0..1 (M)
  const int wc = wid & 3;             // 0..3 (N)

  int orig = blockIdx.x;
  int xcd, nbl, m0;
  if (orig < 256) {                   // heavy q/k: 256x256
    xcd = orig & 7; int j = orig >> 3;
    nbl = j >> 2;
    m0 = (j & 3) * 256;               // 0..768
  } else {                            // light v: 128x256
    int o = orig - 256;
    xcd = o & 7; int j = o >> 3;      // 0..31
    nbl = j >> 2;
    m0 = 1024 + (j & 3) * 128;        // 1024..1408
  }
  const int nb = xcd * 8 + nbl;
  const int n0 = nb * 256;
  const int bidx = n0 >> 12;
  const int nl0 = n0 & (CN - 1);
  const int h0 = nl0 >> 6;

  const int srow = tid >> 2;          // 0..127
  const int scu = tid & 3;
  const int scuS = scu ^ ((srow >> 1) & 3);
  const int d8 = (scuS & 1) ? -16 : 16;
  const size_t pixOfs = (((size_t)(bidx * 66 + h0 + (srow >> 6))) * 66 + (srow & 63)) * 512;
  const unsigned short* gAh0 = Ahi + (size_t)(m0 + srow) * K1 + scuS * 8;
  const unsigned short* gAh1 = gAh0 + (size_t)128 * K1;
  const unsigned short* gBh0 = Xhi + pixOfs + scuS * 8;
  const unsigned short* gBh1 = gBh0 + (size_t)2 * 66 * 512;
  const unsigned char* gA80 = A8 + (size_t)(m0 + srow) * 9216 + scuS * 16;
  const unsigned char* gA81 = gA80 + (size_t)128 * 9216;
  const unsigned char* gB80 = X8 + pixOfs + scuS * 16;
  const unsigned char* gB81 = gB80 + (size_t)2 * 66 * 512;
  const int wofs = wid * 1024;

  int c0S = 0, kxS = 0, tapS = 0;
  size_t tapOfs = 0;
  auto stage1 = [&](int slot) {       // heavy: 4 loads
    int aOfs = tapS * 512 + c0S;
    size_t bOfs = tapOfs + (size_t)c0S;
    unsigned char* lA = smem + slot * 32768 + wofs;
    unsigned char* lB = smem + slot * 32768 + 16384 + wofs;
    g2lds16(gAh0 + aOfs, lA);
    g2lds16(gAh1 + aOfs, lA + 8192);
    g2lds16(gBh0 + bOfs, lB);
    g2lds16(gBh1 + bOfs, lB + 8192);
    c0S += 32;
    if (c0S == 512) {
      c0S = 0; ++tapS;
      if (kxS == 2) { kxS = 0; tapOfs += (size_t)64 * 512; }
      else { ++kxS; tapOfs += 512; }
    }
  };
  auto stage1v = [&](int slot) {      // light: 3 loads (A is 128 rows)
    int aOfs = tapS * 512 + c0S;
    size_t bOfs = tapOfs + (size_t)c0S;
    unsigned char* lA = smem + slot * 32768 + wofs;
    unsigned char* lB = smem + slot * 32768 + 16384 + wofs;
    g2lds16(gAh0 + aOfs, lA);
    g2lds16(gBh0 + bOfs, lB);
    g2lds16(gBh1 + bOfs, lB + 8192);
    c0S += 32;
    if (c0S == 512) {
      c0S = 0; ++tapS;
      if (kxS == 2) { kxS = 0; tapOfs += (size_t)64 * 512; }
      else { ++kxS; tapOfs += 512; }
    }
  };
  int c8 = 0, kx8 = 0, tap8 = 0, s8 = 0;
  size_t tapOfs8 = 0;
  auto stage2 = [&](int slot) {
    int so = (slot & 1) ? d8 : 0;
    int aOfs = s8 * 4608 + tap8 * 512 + c8;
    size_t bOfs = (size_t)s8 * XSPLIT + tapOfs8 + (size_t)c8;
    unsigned char* lA = smem + slot * 32768 + wofs;
    unsigned char* lB = smem + slot * 32768 + 16384 + wofs;
    g2lds16(gA80 + aOfs + so, lA);
    g2lds16(gA81 + aOfs + so, lA + 8192);
    g2lds16(gB80 + bOfs + so, lB);
    g2lds16(gB81 + bOfs + so, lB + 8192);
    c8 += 64;
    if (c8 == 512) {
      c8 = 0; ++tap8;
      if (tap8 == 9) { tap8 = 0; kx8 = 0; tapOfs8 = 0; ++s8; }
      else if (kx8 == 2) { kx8 = 0; tapOfs8 += (size_t)64 * 512; }
      else { ++kx8; tapOfs8 += 512; }
    }
  };

  f32x4 acc[8][4];
  const f32x4 fz = {0.f, 0.f, 0.f, 0.f};
#pragma unroll
  for (int i = 0; i < 8; ++i)
#pragma unroll
    for (int j = 0; j < 4; ++j) acc[i][j] = fz;

  const int kq = (lane >> 4) * 16;
  int slotC, slotS, t2;

  if (m0 < 1024) {
    const int rA = wr * 128 + (lane & 15);
    const int rB = wc * 64 + (lane & 15);
    const int kqA = kq ^ (((rA >> 1) & 3) << 4);
    const int kqB = kq ^ (((rB >> 1) & 3) << 4);

    stage1(0);
    stage1(1);
    asm volatile("s_waitcnt vmcnt(4)" ::: "memory");
    SCHED(); SBAR(); SCHED();
    {
      bf16x8 afA[4], bfA[4], afB[4], bfB[4], af1[4];
#pragma unroll
      for (int mf = 0; mf < 4; ++mf)
        afA[mf] = *(const bf16x8*)(smem + (rA + mf * 16) * 64 + kqA);
#pragma unroll
      for (int nf = 0; nf < 4; ++nf)
        bfA[nf] = *(const bf16x8*)(smem + 16384 + (rB + nf * 16) * 64 + kqB);
      slotC = 0; slotS = 2; t2 = 2;

#define CONV_BF(CURA, CURB, NXTA, NXTB)                                       \
  {                                                                           \
    if (t2 < 144) {                                                           \
      stage1(slotS); slotS = (slotS + 1) & 3;                                 \
      asm volatile("s_waitcnt vmcnt(4)" ::: "memory");                        \
    } else {                                                                  \
      asm volatile("s_waitcnt vmcnt(0)" ::: "memory");                        \
    }                                                                         \
    SCHED(); SBAR(); SCHED();                                                 \
    const unsigned char* lA = smem + slotC * 32768;                           \
    const int slotN = (slotC + 1) & 3;                                        \
    const unsigned char* lAn = smem + slotN * 32768;                          \
    _Pragma("unroll")                                                         \
    for (int mf = 0; mf < 4; ++mf)                                            \
      af1[mf] = *(const bf16x8*)(lA + (rA + 64 + mf * 16) * 64 + kqA);        \
    __builtin_amdgcn_s_setprio(1);                                            \
    _Pragma("unroll")                                                         \
    for (int mf = 0; mf < 4; ++mf) {                                          \
      _Pragma("unroll")                                                       \
      for (int nf = 0; nf < 4; ++nf)                                          \
        acc[mf][nf] = __builtin_amdgcn_mfma_f32_16x16x32_bf16(                \
            CURA[mf], CURB[nf], acc[mf][nf], 0, 0, 0);                        \
    }                                                                         \
    _Pragma("unroll")                                                         \
    for (int mf = 0; mf < 4; ++mf)                                            \
      NXTA[mf] = *(const bf16x8*)(lAn + (rA + mf * 16) * 64 + kqA);           \
    _Pragma("unroll")                                                         \
    for (int nf = 0; nf < 4; ++nf)                                            \
      NXTB[nf] = *(const bf16x8*)(lAn + 16384 + (rB + nf * 16) * 64 + kqB);   \
    _Pragma("unroll")                                                         \
    for (int mf = 0; mf < 4; ++mf) {                                          \
      _Pragma("unroll")                                                       \
      for (int nf = 0; nf < 4; ++nf)                                          \
        acc[mf + 4][nf] = __builtin_amdgcn_mfma_f32_16x16x32_bf16(            \
            af1[mf], CURB[nf], acc[mf + 4][nf], 0, 0, 0);                     \
    }                                                                         \
    __builtin_amdgcn_s_setprio(0);                                            \
    slotC = slotN;                                                            \
    ++t2;                                                                     \
  }

      for (int t = 0; t < 144; t += 2) {
        CONV_BF(afA, bfA, afB, bfB)
        CONV_BF(afB, bfB, afA, bfA)
      }
#undef CONV_BF
    }

    // ---- phase 2': scaled fp8, 72 pair-bodies of K=128 ----
    stage2(0); stage2(1);
    SCHED(); SBAR(); SCHED();
    stage2(2); stage2(3);
    {
      const int gq = lane >> 4;
      const int slotByte = (gq >> 1) << 15;
      const int cb2 = (gq & 1) * 2;
      const int fx = (((lane & 15) >> 1) & 3) ^ (gq >> 1);
      const int bo0 = ((cb2 ^ fx) << 4);
      const int bo1 = (((cb2 + 1) ^ fx) << 4);
      const int aRow = wr * 128 + (lane & 15);
      const int bRow = wc * 64 + (lane & 15);
      i32x8 aF[4], bF[4];
      for (int p = 0; p < 72; ++p) {
        SCHED(); SBAR(); SCHED();
        if (p < 71) { asm volatile("s_waitcnt vmcnt(8)" ::: "memory"); }
        else        { asm volatile("s_waitcnt vmcnt(0)" ::: "memory"); }
        SCHED();
        const unsigned char* pbA = smem + ((p & 1) << 16) + slotByte + aRow * 64;
        const unsigned char* pbB = smem + ((p & 1) << 16) + slotByte + 16384 + bRow * 64;
#pragma unroll
        for (int t = 0; t < 4; ++t) {
          *(i32x4*)&bF[t] = *(const i32x4*)(pbB + t * 1024 + bo0);
          *((i32x4*)&bF[t] + 1) = *(const i32x4*)(pbB + t * 1024 + bo1);
        }
#pragma unroll
        for (int s = 0; s < 4; ++s) {
          *(i32x4*)&aF[s] = *(const i32x4*)(pbA + s * 1024 + bo0);
          *((i32x4*)&aF[s] + 1) = *(const i32x4*)(pbA + s * 1024 + bo1);
        }
        __builtin_amdgcn_s_setprio(1);
#pragma unroll
        for (int s = 0; s < 4; ++s)
#pragma unroll
          for (int t = 0; t < 4; ++t)
            acc[s][t] = __builtin_amdgcn_mfma_scale_f32_16x16x128_f8f6f4(
                aF[s], bF[t], acc[s][t], 0, 0, 0, 127, 0, 127);
#pragma unroll
        for (int s = 0; s < 4; ++s) {
          *(i32x4*)&aF[s] = *(const i32x4*)(pbA + (4 + s) * 1024 + bo0);
          *((i32x4*)&aF[s] + 1) = *(const i32x4*)(pbA + (4 + s) * 1024 + bo1);
        }
#pragma unroll
        for (int s = 0; s < 4; ++s)
#pragma unroll
          for (int t = 0; t < 4; ++t)
            acc[s + 4][t] = __builtin_amdgcn_mfma_scale_f32_16x16x128_f8f6f4(
                aF[s], bF[t], acc[s + 4][t], 0, 0, 0, 127, 0, 127);
        __builtin_amdgcn_s_setprio(0);
        SCHED(); SBAR(); SCHED();
        if (p + 2 < 72) { stage2(2 * (p & 1)); stage2(2 * (p & 1) + 1); }
      }
    }
  } else {
    // =================== LIGHT v: 128x256, bf16 s0 only ====================
    const int rAv = wr * 64 + (lane & 15);
    const int rB = wc * 64 + (lane & 15);
    const int kqA = kq ^ (((rAv >> 1) & 3) << 4);
    const int kqB = kq ^ (((rB >> 1) & 3) << 4);

    stage1v(0);
    stage1v(1);
    asm volatile("s_waitcnt vmcnt(3)" ::: "memory");
    SCHED(); SBAR(); SCHED();
    bf16x8 afA[4], bfA[4], afB[4], bfB[4];
#pragma unroll
    for (int mf = 0; mf < 4; ++mf)
      afA[mf] = *(const bf16x8*)(smem + (rAv + mf * 16) * 64 + kqA);
#pragma unroll
    for (int nf = 0; nf < 4; ++nf)
      bfA[nf] = *(const bf16x8*)(smem + 16384 + (rB + nf * 16) * 64 + kqB);
    slotC = 0; slotS = 2; t2 = 2;

#define CONV_LV(CURA, CURB, NXTA, NXTB)                                       \
  {                                                                           \
    if (t2 < 144) {                                                           \
      stage1v(slotS); slotS = (slotS + 1) & 3;                                \
      asm volatile("s_waitcnt vmcnt(3)" ::: "memory");                        \
    } else {                                                                  \
      asm volatile("s_waitcnt vmcnt(0)" ::: "memory");                        \
    }                                                                         \
    SCHED(); SBAR(); SCHED();                                                 \
    const int slotN = (slotC + 1) & 3;                                        \
    const unsigned char* lAn = smem + slotN * 32768;                          \
    _Pragma("unroll")                                                         \
    for (int mf = 0; mf < 4; ++mf)                                            \
      NXTA[mf] = *(const bf16x8*)(lAn + (rAv + mf * 16) * 64 + kqA);          \
    _Pragma("unroll")                                                         \
    for (int nf = 0; nf < 4; ++nf)                                            \
      NXTB[nf] = *(const bf16x8*)(lAn + 16384 + (rB + nf * 16) * 64 + kqB);   \
    __builtin_amdgcn_s_setprio(1);                                            \
    _Pragma("unroll")                                                         \
    for (int mf = 0; mf < 4; ++mf) {                                          \
      _Pragma("unroll")                                                       \
      for (int nf = 0; nf < 4; ++nf)                                          \
        acc[mf][nf] = __builtin_amdgcn_mfma_f32_16x16x32_bf16(                \
            CURA[mf], CURB[nf], acc[mf][nf], 0, 0, 0);                        \
    }                                                                         \
    __builtin_amdgcn_s_setprio(0);                                            \
    slotC = slotN;                                                            \
    ++t2;                                                                     \
  }

    for (int t = 0; t < 144; t += 2) {
      CONV_LV(afA, bfA, afB, bfB)
      CONV_LV(afB, bfB, afA, bfA)
    }
#undef CONV_LV
  }

  // ---- epilogue: all products at scale 2^14 -> * 2^-14 ----
  constexpr float SC = 1.f / 16384.f;
  if (m0 < 1024) {
#pragma unroll
    for (int mf = 0; mf < 8; ++mf) {
#pragma unroll
      for (int nf = 0; nf < 4; ++nf) {
        f32x4 a = acc[mf][nf];
        int mrow = m0 + wr * 128 + mf * 16 + ((lane >> 4) << 2);
        int ncol = nl0 + wc * 64 + nf * 16 + (lane & 15);
        if (m0 < 512) {
#pragma unroll
          for (int j = 0; j < 4; ++j) {
            float v = a[j] * SC + bias[mrow + j];
            unsigned short h16 = f2bf(v);
            size_t o = ((size_t)bidx * CC + (mrow + j)) * CN + ncol;
            Qhi[o] = h16;
            Qlo[o] = f2bf(v - bf2f(h16));
          }
        } else {
#pragma unroll
          for (int j = 0; j < 4; ++j) {
            float v = a[j] * SC + bias[mrow + j];
            unsigned short h16 = f2bf(v);
            size_t o = ((size_t)bidx * CC + (mrow + j - 512)) * CN + ncol;
            Khi[o] = h16;
            Klo[o] = f2bf(v - bf2f(h16));
          }
        }
      }
    }
  } else {
#pragma unroll
    for (int mf = 0; mf < 4; ++mf) {
#pragma unroll
      for (int nf = 0; nf < 4; ++nf) {
        f32x4 a = acc[mf][nf];
        int mrow = m0 + wr * 64 + mf * 16 + ((lane >> 4) << 2);
        int ncol = nl0 + wc * 64 + nf * 16 + (lane & 15);
        u16x4 vs;                     // V written transposed: Vt[b][n][d]
#pragma unroll
        for (int j = 0; j < 4; ++j) vs[j] = f2bf(a[j] * SC + bias[mrow + j]);
        *(u16x4*)&Vt[((size_t)bidx * CN + ncol) * CC + (mrow - 1024)] = vs;
      }
    }
  }
}

// ---- QK^T: 4-slot/1-barrier template (r14, unchanged) ----------------------
__global__ __launch_bounds__(512, 2) void qk_k(
    const unsigned short* __restrict__ Qhi, const unsigned short* __restrict__ Qlo,
    const unsigned short* __restrict__ Khi, const unsigned short* __restrict__ Klo,
    float* __restrict__ attn)
{
  __shared__ __align__(16) unsigned char smem[4 * 24576];
  const int tid = threadIdx.x;
  const int lane = tid & 63;
  const int wid = tid >> 6;
  const int wr = wid >> 2;
  const int wc = wid & 3;

  int orig = blockIdx.x;              // 0..63
  int work = (orig & 7) * 8 + (orig >> 3);
  const int mt = work & 3;
  const int nt = (work >> 2) & 1;
  const int ks = work >> 3;           // 0..7
  const int bidx = blockIdx.z;
  const int m0 = mt * 128;
  const int n0 = nt * 256;

  const int srow = tid >> 2;
  const int scu = tid & 3;
  const int scuS = scu ^ ((srow >> 1) & 3);
  const size_t rowA = ((size_t)bidx * CC + m0 + srow) * CN + scuS * 8;
  const size_t rowB = ((size_t)bidx * CC + n0 + srow) * CN + scuS * 8;
  const size_t rowB2 = rowB + (size_t)128 * CN;
  const int wofs = wid * 1024;

  int kk = ks * 1536;
  auto stageQ = [&](int slot) {
    int ph = kk >> 12;
    int kin = kk & (CN - 1);
    const unsigned short* Aq = (ph == 2) ? Qlo : Qhi;
    const unsigned short* Bk = (ph == 1) ? Klo : Khi;
    unsigned char* lA = smem + slot * 24576 + wofs;
    unsigned char* lB = smem + slot * 24576 + 8192 + wofs;
    g2lds16(Aq + rowA + kin, lA);
    g2lds16(Bk + rowB + kin, lB);
    g2lds16(Bk + rowB2 + kin, lB + 8192);
    kk += 32;
  };

  f32x4 acc[4][4];
  const f32x4 fz = {0.f, 0.f, 0.f, 0.f};
#pragma unroll
  for (int i = 0; i < 4; ++i)
#pragma unroll
    for (int j = 0; j < 4; ++j) acc[i][j] = fz;

  const int rAv = wr * 64 + (lane & 15);
  const int rB = wc * 64 + (lane & 15);
  const int kq = (lane >> 4) * 16;
  const int kqA = kq ^ (((rAv >> 1) & 3) << 4);
  const int kqB = kq ^ (((rB >> 1) & 3) << 4);

  stageQ(0);
  stageQ(1);
  asm volatile("s_waitcnt vmcnt(3)" ::: "memory");
  SCHED(); SBAR(); SCHED();
  bf16x8 afA[4], bfA[4], afB[4], bfB[4];
#pragma unroll
  for (int mf = 0; mf < 4; ++mf)
    afA[mf] = *(const bf16x8*)(smem + (rAv + mf * 16) * 64 + kqA);
#pragma unroll
  for (int nf = 0; nf < 4; ++nf)
    bfA[nf] = *(const bf16x8*)(smem + 8192 + (rB + nf * 16) * 64 + kqB);
  int slotC = 0, slotS = 2, t2 = 2;

#define QK_BODY(CURA, CURB, NXTA, NXTB)                                       \
  {                                                                           \
    if (t2 < 48) {                                                            \
      stageQ(slotS); slotS = (slotS + 1) & 3;                                 \
      asm volatile("s_waitcnt vmcnt(3)" ::: "memory");                        \
    } else {                                                                  \
      asm volatile("s_waitcnt vmcnt(0)" ::: "memory");                        \
    }                                                                         \
    SCHED(); SBAR(); SCHED();                                                 \
    const int slotN = (slotC + 1) & 3;                                        \
    const unsigned char* lAn = smem + slotN * 24576;                          \
    _Pragma("unroll")                                                         \
    for (int mf = 0; mf < 4; ++mf)                                            \
      NXTA[mf] = *(const bf16x8*)(lAn + (rAv + mf * 16) * 64 + kqA);          \
    _Pragma("unroll")                                                         \
    for (int nf = 0; nf < 4; ++nf)                                            \
      NXTB[nf] = *(const bf16x8*)(lAn + 8192 + (rB + nf * 16) * 64 + kqB);    \
    __builtin_amdgcn_s_setprio(1);                                            \
    _Pragma("unroll")                                                         \
    for (int mf = 0; mf < 4; ++mf) {                                          \
      _Pragma("unroll")                                                       \
      for (int nf = 0; nf < 4; ++nf)                                          \
        acc[mf][nf] = __builtin_amdgcn_mfma_f32_16x16x32_bf16(                \
            CURA[mf], CURB[nf], acc[mf][nf], 0, 0, 0);                        \
    }                                                                         \
    __builtin_amdgcn_s_setprio(0);                                            \
    slotC = slotN;                                                            \
    ++t2;                                                                     \
  }

  for (int t = 0; t < 48; t += 2) {
    QK_BODY(afA, bfA, afB, bfB)
    QK_BODY(afB, bfB, afA, bfA)
  }
#undef QK_BODY

  size_t pbase = (size_t)ks * ((size_t)BCH * CC * CC);
#pragma unroll
  for (int mf = 0; mf < 4; ++mf) {
#pragma unroll
    for (int nf = 0; nf < 4; ++nf) {
      f32x4 a = acc[mf][nf];
      int mrow = m0 + wr * 64 + mf * 16 + ((lane >> 4) << 2);
      int ncol = n0 + wc * 64 + nf * 16 + (lane & 15);
#pragma unroll
      for (int j = 0; j < 4; ++j)
        attn[pbase + ((size_t)bidx * CC + (mrow + j)) * CC + ncol] = a[j];
    }
  }
}

// ---- PV: r17 port onto the same 4-slot template (128x256 tile, 16 ktiles) --
__global__ __launch_bounds__(512, 2) void pv_k(
    const unsigned short* __restrict__ Vt,
    const unsigned short* __restrict__ P,
    const float* __restrict__ xin,
    const float* __restrict__ gamma,
    float* __restrict__ out)
{
  __shared__ __align__(16) unsigned char smem[4 * 24576];
  const int tid = threadIdx.x;
  const int lane = tid & 63;
  const int wid = tid >> 6;
  const int wr = wid >> 2;
  const int wc = wid & 3;

  int orig = blockIdx.x;              // 0..63
  int work = (orig & 7) * 8 + (orig >> 3);
  const int mt = work & 3;            // M tiles: 512/128
  const int nt = work >> 2;           // N tiles: 4096/256 = 16
  const int bidx = blockIdx.z;
  const int m0 = mt * 128;
  const int n0 = nt * 256;

  const int srow = tid >> 2;
  const int scu = tid & 3;
  const int scuS = scu ^ ((srow >> 1) & 3);
  const size_t rowA = ((size_t)bidx * CC + m0 + srow) * CC + scuS * 8;
  const size_t rowB = ((size_t)bidx * CN + n0 + srow) * CC + scuS * 8;
  const size_t rowB2 = rowB + (size_t)128 * CC;
  const int wofs = wid * 1024;

  int kk = 0;
  auto stageP = [&](int slot) {
    unsigned char* lA = smem + slot * 24576 + wofs;
    unsigned char* lB = smem + slot * 24576 + 8192 + wofs;
    g2lds16(P + rowA + kk, lA);
    g2lds16(Vt + rowB + kk, lB);
    g2lds16(Vt + rowB2 + kk, lB + 8192);
    kk += 32;
  };

  f32x4 acc[4][4];
  const f32x4 fz = {0.f, 0.f, 0.f, 0.f};
#pragma unroll
  for (int i = 0; i < 4; ++i)
#pragma unroll
    for (int j = 0; j < 4; ++j) acc[i][j] = fz;

  const int rAv = wr * 64 + (lane & 15);
  const int rB = wc * 64 + (lane & 15);
  const int kq = (lane >> 4) * 16;
  const int kqA = kq ^ (((rAv >> 1) & 3) << 4);
  const int kqB = kq ^ (((rB >> 1) & 3) << 4);

  stageP(0);
  stageP(1);
  asm volatile("s_waitcnt vmcnt(3)" ::: "memory");
  SCHED(); SBAR(); SCHED();
  bf16x8 afA[4], bfA[4], afB[4], bfB[4];
#pragma unroll
  for (int mf = 0; mf < 4; ++mf)
    afA[mf] = *(const bf16x8*)(smem + (rAv + mf * 16) * 64 + kqA);
#pragma unroll
  for (int nf = 0; nf < 4; ++nf)
    bfA[nf] = *(const bf16x8*)(smem + 8192 + (rB + nf * 16) * 64 + kqB);
  int slotC = 0, slotS = 2, t2 = 2;

#define PV_BODY(CURA, CURB, NXTA, NXTB)                                       \
  {                                                                           \
    if (t2 < 16) {                                                            \
      stageP(slotS); slotS = (slotS + 1) & 3;                                 \
      asm volatile("s_waitcnt vmcnt(3)" ::: "memory");                        \
    } else {                                                                  \
      asm volatile("s_waitcnt vmcnt(0)" ::: "memory");                        \
    }                                                                         \
    SCHED(); SBAR(); SCHED();                                                 \
    const int slotN = (slotC + 1) & 3;                                        \
    const unsigned char* lAn = smem + slotN * 24576;                          \
    _Pragma("unroll")                                                         \
    for (int mf = 0; mf < 4; ++mf)                                            \
      NXTA[mf] = *(const bf16x8*)(lAn + (rAv + mf * 16) * 64 + kqA);          \
    _Pragma("unroll")                                                         \
    for (int nf = 0; nf < 4; ++nf)                                            \
      NXTB[nf] = *(const bf16x8*)(lAn + 8192 + (rB + nf * 16) * 64 + kqB);    \
    __builtin_amdgcn_s_setprio(1);                                            \
    _Pragma("unroll")                                                         \
    for (int mf = 0; mf < 4; ++mf) {                                          \
      _Pragma("unroll")                                                       \
      for (int nf = 0; nf < 4; ++nf)                                          \
        acc[mf][nf] = __builtin_amdgcn_mfma_f32_16x16x32_bf16(                \
            CURA[mf], CURB[nf], acc[mf][nf], 0, 0, 0);                        \
    }                                                                         \
    __builtin_amdgcn_s_setprio(0);                                            \
    slotC = slotN;                                                            \
    ++t2;                                                                     \
  }

  for (int t = 0; t < 16; t += 2) {
    PV_BODY(afA, bfA, afB, bfB)
    PV_BODY(afB, bfB, afA, bfA)
  }
#undef PV_BODY

  float g = gamma[0];
#pragma unroll
  for (int mf = 0; mf < 4; ++mf) {
#pragma unroll
    for (int nf = 0; nf < 4; ++nf) {
      f32x4 a = acc[mf][nf];
      int mrow = m0 + wr * 64 + mf * 16 + ((lane >> 4) << 2);
      int ncol = n0 + wc * 64 + nf * 16 + (lane & 15);
#pragma unroll
      for (int j = 0; j < 4; ++j) {
        size_t o = ((size_t)bidx * CC + (mrow + j)) * CN + ncol;
        out[o] = g * a[j] + xin[o];
      }
    }
  }
}

// ---- softmax over d (512): sum KSPL split-K partials, one wave per row -----
__global__ __launch_bounds__(256) void softmax_k(const float* __restrict__ attn,
                                                 unsigned short* __restrict__ P) {
  int row = blockIdx.x * 4 + (threadIdx.x >> 6);
  int lane = threadIdx.x & 63;
  constexpr size_t PS = (size_t)BCH * CC * CC;
  const float* rp = attn + (size_t)row * 512 + lane * 8;
  f32x4 a = {0.f, 0.f, 0.f, 0.f};
  f32x4 b = {0.f, 0.f, 0.f, 0.f};
#pragma unroll
  for (int ksp = 0; ksp < KSPL; ++ksp) {
    a += *(const f32x4*)(rp + (size_t)ksp * PS);
    b += *(const f32x4*)(rp + (size_t)ksp * PS + 4);
  }
  float mx = fmaxf(fmaxf(fmaxf(a[0], a[1]), fmaxf(a[2], a[3])),
                   fmaxf(fmaxf(b[0], b[1]), fmaxf(b[2], b[3])));
#pragma unroll
  for (int s = 32; s > 0; s >>= 1) mx = fmaxf(mx, __shfl_xor(mx, s, 64));
  float e[8];
  float sum = 0.f;
#pragma unroll
  for (int j = 0; j < 4; ++j) { e[j] = __expf(a[j] - mx); sum += e[j]; }
#pragma unroll
  for (int j = 0; j < 4; ++j) { e[4 + j] = __expf(b[j] - mx); sum += e[4 + j]; }
#pragma unroll
  for (int s = 32; s > 0; s >>= 1) sum += __shfl_xor(sum, s, 64);
  float inv = 1.0f / sum;
  u16x8 o;
#pragma unroll
  for (int j = 0; j < 8; ++j) o[j] = f2bf(e[j] * inv);
  *(u16x8*)&P[(size_t)row * 512 + lane * 8] = o;
}

// ---- diagnostic: fill out with sentinel if workspace is too small ----------
__global__ __launch_bounds__(256) void fill_sentinel(float* __restrict__ out, int n) {
  int i = blockIdx.x * 256 + threadIdx.x;
  if (i < n) out[i] = 1.0e4f;
}

// ---------------------------------------------------------------------------
extern "C" void kernel_launch(void* const* d_in, const int* in_sizes, int n_in,
                              void* d_out, int out_size, void* d_ws, size_t ws_size,
                              hipStream_t stream) {
  (void)in_sizes; (void)n_in;
  const float* x  = (const float*)d_in[0];
  const float* wq = (const float*)d_in[1];
  const float* bq = (const float*)d_in[2];
  const float* wk = (const float*)d_in[3];
  const float* bk = (const float*)d_in[4];
  const float* wv = (const float*)d_in[5];
  const float* bv = (const float*)d_in[6];
  const float* gm = (const float*)d_in[7];
  float* out = (float*)d_out;

  uint8_t* wsp = (uint8_t*)d_ws;
  auto take = [&](size_t bytes) {
    uint8_t* p = wsp;
    wsp += (bytes + 255) & ~(size_t)255;
    return p;
  };
  unsigned short* Xhi = (unsigned short*)take(XSPLIT * 2);          // 17.8 MB
  unsigned char*  X8  = (unsigned char*)take(2 * XSPLIT);           // 35.7 MB
  unsigned short* Ahi = (unsigned short*)take((size_t)MR * K1 * 2); // 13.5 MB
  unsigned char*  A8  = (unsigned char*)take((size_t)MR * 2 * K1);  // 13.5 MB
  float* bias         = (float*)take((size_t)MR * 4);
  unsigned short* Khi = (unsigned short*)take((size_t)BCH * CC * CN * 2);  // 16.8 MB
  unsigned short* Klo = (unsigned short*)take((size_t)BCH * CC * CN * 2);  // 16.8 MB
  unsigned short* Vt  = (unsigned short*)take((size_t)BCH * CN * CC * 2);  // 16.8 MB
  float* attn         = (float*)Xhi;
  unsigned short* P   = (unsigned short*)((uint8_t*)Xhi +
                          (size_t)KSPL * BCH * CC * CC * 4 + 256);

  size_t needed = (size_t)(wsp - (uint8_t*)d_ws);   // ~113 MB
  if (ws_size < needed) {
    fill_sentinel<<<(out_size + 255) / 256, 256, 0, stream>>>(out, out_size);
    return;
  }

  for (int ch = 0; ch < CB / BCH; ++ch) {
    const float* xch = x + (size_t)ch * BCH * CC * CN;
    float* outch = out + (size_t)ch * BCH * CC * CN;
    unsigned short* Qhi = (unsigned short*)outch;   // Q pair lives in d_out
    unsigned short* Qlo = Qhi + (size_t)BCH * CC * CN;

    pad_zero<<<(4 * 260 * 16 + 255) / 256, 256, 0, stream>>>(Xhi, X8);
    prep_xpad<<<BCH * 16 * 64, 256, 0, stream>>>(xch, Xhi, X8);
    if (ch == 0)
      prep_abig<<<(MR * K1) / 256, 256, 0, stream>>>(wq, wk, wv, bq, bk, bv,
                                                     Ahi, A8, bias);
    conv_k<<<dim3(512), 512, 0, stream>>>(Ahi, A8, Xhi, X8, bias,
                                          Qhi, Qlo, Khi, Klo, Vt);
    qk_k<<<dim3(64, 1, BCH), 512, 0, stream>>>(Qhi, Qlo, Khi, Klo, attn);
    softmax_k<<<BCH * 128, 256, 0, stream>>>(attn, P);
    pv_k<<<dim3(64, 1, BCH), 512, 0, stream>>>(Vt, P, xch, gm, outch);
  }
}